// Round 12
// baseline (2852.435 us; speedup 1.0000x reference)
//
#include <hip/hip_runtime.h>

// Encoder: 2-layer LSTM (H1=64, H2=32, IN=2), B=512, T=4096, + FC [32->16].
// R24 = R22 (best: 1483.7us) with TWO batch elements interleaved per wave.
//  - R22 is latency-bound: ~300cy real issue in a ~940cy step (VALUBusy 74%
//    is the gfx94x 4-cy formula; real ~37%). The ~600cy stall needs work
//    independent of the current step -> a SECOND batch element's recurrence,
//    sharing the same resident weights (batch shares W!).
//  - L1 wave = L1(be0)+L1(be1), instruction-interleaved inside ONE step
//    macro: 16 ds_read_b128 issued up front, dot groups alternate be0/be1
//    (8 independent accumulator chains), two independent activation chains.
//    (R17's fusion failed as two MACRO-sequential latency chains; this is
//    fine-grain interleave in a single basic block.)
//  - L2 wave = L2(be0)+L2(be1), same idea; drops R22's Ha/Hb double-buffer
//    (be-interleave now hides the streaming-read latency). Reg G-exchange
//    per be kept (R21).
//  - verified per-be exchanges kept: L1 h via LDS ring (R23 A/B: reg is
//    worse), L2 h2 via registers, x via readlane, 1 barrier per 64-step
//    chunk, pre-scaled gates. Block = 128 thr {L1 pair, L2 pair}, grid 256.
//    Math per be bit-identical to R22 -> absmax unchanged.

#define TT 4096
#define BB 512
#define NCH 64   // chunks of 64 steps

typedef float    f4  __attribute__((ext_vector_type(4)));
typedef int      i4  __attribute__((ext_vector_type(4)));
typedef _Float16 h2v __attribute__((ext_vector_type(2)));
typedef _Float16 h8  __attribute__((ext_vector_type(8)));   // 4 VGPRs

__device__ __forceinline__ float fexp2(float x){ return __builtin_amdgcn_exp2f(x); }
__device__ __forceinline__ float frcp (float x){ return __builtin_amdgcn_rcpf(x); }
// logistic on a PRE-SCALED argument (scale folded into weights/bias).
__device__ __forceinline__ float lgs  (float p){ return frcp(1.0f + fexp2(p)); }
__device__ __forceinline__ float tanh_(float x){ return 1.0f - 2.0f * frcp(1.0f + fexp2(x * 2.8853900817779268f)); }

// Lightweight barrier: LDS-drain only; leaves global prefetch in flight.
#define BARRIER() asm volatile("s_waitcnt lgkmcnt(0)\n\ts_barrier" ::: "memory")

// DPP move. 0xB1=[1,0,3,2] within quads.
template<int CTRL>
__device__ __forceinline__ float qperm(float v){
  const int s = __builtin_bit_cast(int, v);
  return __builtin_bit_cast(float, __builtin_amdgcn_update_dpp(s, s, CTRL, 0xF, 0xF, true));
}
__device__ __forceinline__ h2v bch(int s){ return __builtin_bit_cast(h2v, s); }
__device__ __forceinline__ float dot8(h8 a, i4 bi, float c){
  const i4 ai = __builtin_bit_cast(i4, a);
  c = __builtin_amdgcn_fdot2(bch(ai.x), bch(bi.x), c, false);
  c = __builtin_amdgcn_fdot2(bch(ai.y), bch(bi.y), c, false);
  c = __builtin_amdgcn_fdot2(bch(ai.z), bch(bi.z), c, false);
  c = __builtin_amdgcn_fdot2(bch(ai.w), bch(bi.w), c, false);
  return c;
}
__device__ __forceinline__ float fdh(int a, int b, float c){
  return __builtin_amdgcn_fdot2(bch(a), bch(b), c, false);
}
__device__ __forceinline__ int pack16(float a, float b){
  h2v p; p.x = (_Float16)a; p.y = (_Float16)b;
  return __builtin_bit_cast(int, p);
}
__device__ __forceinline__ h8 ldh8s(const float* p, float s){
  const f4 a = ((const f4*)p)[0], b = ((const f4*)p)[1];
  h8 r;
  r[0]=(_Float16)(a.x*s); r[1]=(_Float16)(a.y*s); r[2]=(_Float16)(a.z*s); r[3]=(_Float16)(a.w*s);
  r[4]=(_Float16)(b.x*s); r[5]=(_Float16)(b.y*s); r[6]=(_Float16)(b.z*s); r[7]=(_Float16)(b.w*s);
  return r;
}

extern "C" __global__ __launch_bounds__(128, 1) void lstm_enc_kernel(
    const float* __restrict__ x,
    const float* __restrict__ Wih1, const float* __restrict__ Whh1,
    const float* __restrict__ bih1, const float* __restrict__ bhh1,
    const float* __restrict__ Wih2, const float* __restrict__ Whh2,
    const float* __restrict__ bih2, const float* __restrict__ bhh2,
    const float* __restrict__ Wfc,  const float* __restrict__ bfc,
    float* __restrict__ out)
{
    const int tid = threadIdx.x;
    const int l   = tid & 63;
    const int wv  = __builtin_amdgcn_readfirstlane(tid >> 6);   // 0=L1 pair, 1=L2 pair
    const int bg0 = blockIdx.x * 2;            // this block's two batch elements
    const int bg1 = bg0 + 1;

    // per-be h1 ring: 128 steps (2 chunks x 64), row t%128 = h1(t), 64 fp16.
    __shared__ __align__(16) _Float16 ring[2][128][64];   // 32 KB
    __shared__ __align__(16) _Float16 h2r[2][2][32];      // h2 slots (t&1)

    const float kSs = -1.4426950408889634f;   // sigmoid pre-scale
    const float kSg = -2.8853900817779268f;   // tanh-form pre-scale

    if (wv == 0) {
        // ---------- L1 pair wave: lane u = l owns unit u, be0 AND be1 ----------
        h8 wi[8], wf[8], wg[8], wo[8];
        const int ri = l, rf = 64 + l, rg = 128 + l, ro = 192 + l;
        #pragma unroll
        for (int j = 0; j < 8; ++j) {
            wi[j] = ldh8s(Whh1 + ri*64 + j*8, kSs);
            wf[j] = ldh8s(Whh1 + rf*64 + j*8, kSs);
            wg[j] = ldh8s(Whh1 + rg*64 + j*8, kSg);
            wo[j] = ldh8s(Whh1 + ro*64 + j*8, kSs);
        }
        const int wxi = pack16(Wih1[ri*2]*kSs, Wih1[ri*2+1]*kSs);
        const int wxf = pack16(Wih1[rf*2]*kSs, Wih1[rf*2+1]*kSs);
        const int wxg = pack16(Wih1[rg*2]*kSg, Wih1[rg*2+1]*kSg);
        const int wxo = pack16(Wih1[ro*2]*kSs, Wih1[ro*2+1]*kSs);
        const float bi_ = (bih1[ri] + bhh1[ri]) * kSs;
        const float bf_ = (bih1[rf] + bhh1[rf]) * kSs;
        const float bg_ = (bih1[rg] + bhh1[rg]) * kSg;
        const float bo_ = (bih1[ro] + bhh1[ro]) * kSs;

        // self-loaded x per be: lane s holds pack16(x(t=c*64+s))
        const float2* xb0 = (const float2*)(x + (size_t)bg0 * (TT * 2));
        const float2* xb1 = (const float2*)(x + (size_t)bg1 * (TT * 2));
        const float2 u0 = xb0[l], u1 = xb1[l];
        int vxc0 = pack16(u0.x, u0.y);
        int vxc1 = pack16(u1.x, u1.y);
        float2 vxn0 = xb0[64 + l], vxn1 = xb1[64 + l];

        if (l < 32) {                               // h1(-1) = 0, both rings
            ((int*)&ring[0][127][0])[l] = 0;
            ((int*)&ring[1][127][0])[l] = 0;
        }
        BARRIER();

        float cc0 = 0.f, cc1 = 0.f;
        _Float16* rw0 = &ring[0][0][0];
        _Float16* rw1 = &ring[1][0][0];
        const i4* rd0 = (const i4*)&ring[0][0][0];
        const i4* rd1 = (const i4*)&ring[1][0][0];

// Interleaved pair step: 16 reads issued up front; dot groups alternate
// be0/be1 (8 independent accumulator chains); two independent act chains.
#define L1P(PR, CR, XV0, XV1) { \
    const i4* Hp0 = rd0 + (PR)*8; \
    const i4* Hp1 = rd1 + (PR)*8; \
    i4 H0[8], H1[8]; \
    _Pragma("unroll") for (int j = 0; j < 8; ++j) H0[j] = Hp0[j]; \
    _Pragma("unroll") for (int j = 0; j < 8; ++j) H1[j] = Hp1[j]; \
    float a0i = bi_, a0f = bf_, a0g = bg_, a0o = bo_; \
    float a1i = bi_, a1f = bf_, a1g = bg_, a1o = bo_; \
    _Pragma("unroll") for (int j = 0; j < 8; ++j) { \
        a0i = dot8(wi[j], H0[j], a0i); a0f = dot8(wf[j], H0[j], a0f); \
        a0g = dot8(wg[j], H0[j], a0g); a0o = dot8(wo[j], H0[j], a0o); \
        a1i = dot8(wi[j], H1[j], a1i); a1f = dot8(wf[j], H1[j], a1f); \
        a1g = dot8(wg[j], H1[j], a1g); a1o = dot8(wo[j], H1[j], a1o); } \
    const int xv0_ = (XV0), xv1_ = (XV1); \
    a0i = fdh(wxi, xv0_, a0i); a0f = fdh(wxf, xv0_, a0f); \
    a0g = fdh(wxg, xv0_, a0g); a0o = fdh(wxo, xv0_, a0o); \
    a1i = fdh(wxi, xv1_, a1i); a1f = fdh(wxf, xv1_, a1f); \
    a1g = fdh(wxg, xv1_, a1g); a1o = fdh(wxo, xv1_, a1o); \
    const float gi0 = lgs(a0i), gf0 = lgs(a0f), go0 = lgs(a0o); \
    const float gg0 = fmaf(2.f, lgs(a0g), -1.f); \
    const float gi1 = lgs(a1i), gf1 = lgs(a1f), go1 = lgs(a1o); \
    const float gg1 = fmaf(2.f, lgs(a1g), -1.f); \
    cc0 = fmaf(gf0, cc0, gi0 * gg0); \
    cc1 = fmaf(gf1, cc1, gi1 * gg1); \
    rw0[(CR)*64 + l] = (_Float16)(go0 * tanh_(cc0)); \
    rw1[(CR)*64 + l] = (_Float16)(go1 * tanh_(cc1)); }

        #pragma unroll 1
        for (int c = 0; c <= NCH; ++c) {
            if (c < NCH) {
                const int base = (c & 1) * 64;
                const int p0 = (base ^ 64) + 63;   // last row of other chunk
                L1P(p0, base, __builtin_amdgcn_readlane(vxc0, 0),
                              __builtin_amdgcn_readlane(vxc1, 0))
                #pragma unroll 1
                for (int s = 1; s < 64; ++s) {
                    L1P(base + s - 1, base + s,
                        __builtin_amdgcn_readlane(vxc0, s),
                        __builtin_amdgcn_readlane(vxc1, s))
                }
                // rotate x buffers: pack chunk c+1, prefetch chunk c+2
                if (c + 1 < NCH) { vxc0 = pack16(vxn0.x, vxn0.y); vxc1 = pack16(vxn1.x, vxn1.y); }
                if (c + 2 < NCH) { vxn0 = xb0[(c + 2) * 64 + l]; vxn1 = xb1[(c + 2) * 64 + l]; }
            }
            BARRIER();
        }
#undef L1P
    } else {
        // ---- L2 pair wave: lane = (u = l&31, hf = l>>5); rows (i,f)|(g,o) ----
        const int u = l & 31, hf = l >> 5;
        const float hff = (float)hf;
        const int rA = hf * 64 + u;        // i (hf=0) or g (hf=1)
        const int rB = hf * 64 + 32 + u;   // f (hf=0) or o (hf=1)
        const float kA = hf ? kSg : kSs;
        h8 wa[12], wb[12];
        #pragma unroll
        for (int j = 0; j < 8; ++j) {
            wa[j] = ldh8s(Wih2 + rA*64 + j*8, kA);
            wb[j] = ldh8s(Wih2 + rB*64 + j*8, kSs);
        }
        #pragma unroll
        for (int j = 0; j < 4; ++j) {
            wa[8+j] = ldh8s(Whh2 + rA*32 + j*8, kA);
            wb[8+j] = ldh8s(Whh2 + rB*32 + j*8, kSs);
        }
        const float ba_ = (bih2[rA] + bhh2[rA]) * kA;
        const float bb_ = (bih2[rB] + bhh2[rB]) * kSs;

        BARRIER();

        float c20 = 0.f, c21 = 0.f;
        int hp20 = 0, hp21 = 0;            // packed h2 pairs on even lanes; h2(-1)=0
        const i4* rdh0 = (const i4*)&ring[0][0][0];
        const i4* rdh1 = (const i4*)&ring[1][0][0];
        _Float16* q00 = &h2r[0][0][0];
        _Float16* q01 = &h2r[0][1][0];
        _Float16* q10 = &h2r[1][0][0];
        _Float16* q11 = &h2r[1][1][0];

// Interleaved pair step: 16 jit reads (be-interleave hides their latency),
// dot groups alternate be0/be1, reg G-exchange per be, two act chains.
#define L2P(S, QW0, QW1) { \
    const i4* Hp0 = rc0 + (S)*8; \
    const i4* Hp1 = rc1 + (S)*8; \
    i4 H0[8], H1[8]; \
    _Pragma("unroll") for (int j = 0; j < 8; ++j) H0[j] = Hp0[j]; \
    _Pragma("unroll") for (int j = 0; j < 8; ++j) H1[j] = Hp1[j]; \
    i4 G0[4], G1[4]; \
    _Pragma("unroll") for (int j = 0; j < 4; ++j) { \
        G0[j].x = __builtin_amdgcn_readlane(hp20, j*8+0); \
        G0[j].y = __builtin_amdgcn_readlane(hp20, j*8+2); \
        G0[j].z = __builtin_amdgcn_readlane(hp20, j*8+4); \
        G0[j].w = __builtin_amdgcn_readlane(hp20, j*8+6); \
        G1[j].x = __builtin_amdgcn_readlane(hp21, j*8+0); \
        G1[j].y = __builtin_amdgcn_readlane(hp21, j*8+2); \
        G1[j].z = __builtin_amdgcn_readlane(hp21, j*8+4); \
        G1[j].w = __builtin_amdgcn_readlane(hp21, j*8+6); } \
    float pa0 = ba_, pb0 = bb_, pa1 = ba_, pb1 = bb_; \
    _Pragma("unroll") for (int j = 0; j < 8; ++j) { \
        pa0 = dot8(wa[j], H0[j], pa0); pb0 = dot8(wb[j], H0[j], pb0); \
        pa1 = dot8(wa[j], H1[j], pa1); pb1 = dot8(wb[j], H1[j], pb1); } \
    _Pragma("unroll") for (int j = 0; j < 4; ++j) { \
        pa0 = dot8(wa[8+j], G0[j], pa0); pb0 = dot8(wb[8+j], G0[j], pb0); \
        pa1 = dot8(wa[8+j], G1[j], pa1); pb1 = dot8(wb[8+j], G1[j], pb1); } \
    const float sa0 = lgs(pa0); \
    const float va0 = fmaf(hff, sa0 - 1.f, sa0); \
    const float vb0 = lgs(pb0); \
    const float sa1 = lgs(pa1); \
    const float va1 = fmaf(hff, sa1 - 1.f, sa1); \
    const float vb1 = lgs(pb1); \
    const float oa0 = __shfl_xor(va0, 32); \
    const float ob0 = __shfl_xor(vb0, 32); \
    const float oa1 = __shfl_xor(va1, 32); \
    const float ob1 = __shfl_xor(vb1, 32); \
    const float gi0 = hf ? oa0 : va0, gf0 = hf ? ob0 : vb0; \
    const float gg0 = hf ? va0 : oa0, go0 = hf ? vb0 : ob0; \
    const float gi1 = hf ? oa1 : va1, gf1 = hf ? ob1 : vb1; \
    const float gg1 = hf ? va1 : oa1, go1 = hf ? vb1 : ob1; \
    c20 = fmaf(gf0, c20, gi0 * gg0); \
    c21 = fmaf(gf1, c21, gi1 * gg1); \
    const float h2n0 = go0 * tanh_(c20); \
    const float h2n1 = go1 * tanh_(c21); \
    hp20 = pack16(h2n0, qperm<0xB1>(h2n0)); \
    hp21 = pack16(h2n1, qperm<0xB1>(h2n1)); \
    if (!hf) { (QW0)[u] = (_Float16)h2n0; (QW1)[u] = (_Float16)h2n1; } }

        #pragma unroll 1
        for (int c = 0; c <= NCH; ++c) {
            if (c > 0) {
                const i4* rc0 = rdh0 + ((c - 1) & 1) * 64 * 8;   // chunk c-1 rows
                const i4* rc1 = rdh1 + ((c - 1) & 1) * 64 * 8;
                // tau = (c-1)*64 + s; tau even -> slot 0, odd -> slot 1
                #pragma unroll 1
                for (int s = 0; s < 64; s += 2) {
                    L2P(s,     q00, q10)
                    L2P(s + 1, q01, q11)
                }
            }
            BARRIER();
        }
#undef L2P

        // final h2(TT-1) in h2r[be][1] (4095 odd -> slot 1); lanes 0-15 -> be0,
        // lanes 32-47 -> be1.
        const int fb = l >> 5, fl = l & 31;
        if (fl < 16) {
            float sum = bfc[fl];
            const float* wr = Wfc + fl * 32;
            #pragma unroll
            for (int k = 0; k < 32; ++k) sum = fmaf(wr[k], (float)h2r[fb][1][k], sum);
            out[(bg0 + fb) * 16 + fl] = sum;
        }
    }
}

extern "C" void kernel_launch(void* const* d_in, const int* in_sizes, int n_in,
                              void* d_out, int out_size, void* d_ws, size_t ws_size,
                              hipStream_t stream) {
    const float* x    = (const float*)d_in[0];
    const float* Wih1 = (const float*)d_in[1];
    const float* Whh1 = (const float*)d_in[2];
    const float* bih1 = (const float*)d_in[3];
    const float* bhh1 = (const float*)d_in[4];
    const float* Wih2 = (const float*)d_in[5];
    const float* Whh2 = (const float*)d_in[6];
    const float* bih2 = (const float*)d_in[7];
    const float* bhh2 = (const float*)d_in[8];
    const float* Wfc  = (const float*)d_in[9];
    const float* bfc  = (const float*)d_in[10];

    hipLaunchKernelGGL(lstm_enc_kernel, dim3(BB / 2), dim3(128), 0, stream,
        x, Wih1, Whh1, bih1, bhh1, Wih2, Whh2, bih2, bhh2, Wfc, bfc,
        (float*)d_out);
}

// Round 15
// 1558.337 us; speedup vs baseline: 1.8304x; 1.8304x over previous
//
#include <hip/hip_runtime.h>

// Encoder: 2-layer LSTM (H1=64, H2=32, IN=2), B=512, T=4096, + FC [32->16].
// R27 = R22 (best: 1483.7us) + ONLY the L1 per-j load->dot interleave.
//  - R26 failed correctness (absmax 0.347): my v_permlane32_swap_b32 asm
//    had wrong operand-direction semantics -> no actual lane exchange.
//    LESSON: never ship un-unit-tested permlane asm. L2 restored to the
//    verified __shfl_xor(.,32) path (R16-R22 all passed with it).
//  - L1 cut kept (bit-identical: same instruction stream, only load
//    placement changes): consume Hp[j] inside the dot loop so the compiler
//    emits counted lgkmcnt(7..0) and dots on H[0] start ~50-100cy before
//    the last ds_read_b128 lands.
//  - everything else verbatim R22: L1 LDS h-exchange + x via readlane,
//    L2 reg G-exchange + double-buffered streaming H reads, 128-step ring,
//    1 barrier per 64-step chunk, pre-scaled gates, 256thr = {L1,L2} x 2be,
//    grid 256 (1 block/CU, 1 wave/SIMD).

#define TT 4096
#define BB 512
#define NCH 64   // chunks of 64 steps

typedef float    f4  __attribute__((ext_vector_type(4)));
typedef int      i4  __attribute__((ext_vector_type(4)));
typedef _Float16 h2v __attribute__((ext_vector_type(2)));
typedef _Float16 h8  __attribute__((ext_vector_type(8)));   // 4 VGPRs

__device__ __forceinline__ float fexp2(float x){ return __builtin_amdgcn_exp2f(x); }
__device__ __forceinline__ float frcp (float x){ return __builtin_amdgcn_rcpf(x); }
// logistic on a PRE-SCALED argument (scale folded into weights/bias).
__device__ __forceinline__ float lgs  (float p){ return frcp(1.0f + fexp2(p)); }
__device__ __forceinline__ float tanh_(float x){ return 1.0f - 2.0f * frcp(1.0f + fexp2(x * 2.8853900817779268f)); }

// Lightweight barrier: LDS-drain only; leaves global prefetch in flight.
#define BARRIER() asm volatile("s_waitcnt lgkmcnt(0)\n\ts_barrier" ::: "memory")

// DPP move. 0xB1=[1,0,3,2] within quads.
template<int CTRL>
__device__ __forceinline__ float qperm(float v){
  const int s = __builtin_bit_cast(int, v);
  return __builtin_bit_cast(float, __builtin_amdgcn_update_dpp(s, s, CTRL, 0xF, 0xF, true));
}
__device__ __forceinline__ h2v bch(int s){ return __builtin_bit_cast(h2v, s); }
__device__ __forceinline__ float dot8(h8 a, i4 bi, float c){
  const i4 ai = __builtin_bit_cast(i4, a);
  c = __builtin_amdgcn_fdot2(bch(ai.x), bch(bi.x), c, false);
  c = __builtin_amdgcn_fdot2(bch(ai.y), bch(bi.y), c, false);
  c = __builtin_amdgcn_fdot2(bch(ai.z), bch(bi.z), c, false);
  c = __builtin_amdgcn_fdot2(bch(ai.w), bch(bi.w), c, false);
  return c;
}
__device__ __forceinline__ float fdh(int a, int b, float c){
  return __builtin_amdgcn_fdot2(bch(a), bch(b), c, false);
}
__device__ __forceinline__ int pack16(float a, float b){
  h2v p; p.x = (_Float16)a; p.y = (_Float16)b;
  return __builtin_bit_cast(int, p);
}
__device__ __forceinline__ h8 ldh8s(const float* p, float s){
  const f4 a = ((const f4*)p)[0], b = ((const f4*)p)[1];
  h8 r;
  r[0]=(_Float16)(a.x*s); r[1]=(_Float16)(a.y*s); r[2]=(_Float16)(a.z*s); r[3]=(_Float16)(a.w*s);
  r[4]=(_Float16)(b.x*s); r[5]=(_Float16)(b.y*s); r[6]=(_Float16)(b.z*s); r[7]=(_Float16)(b.w*s);
  return r;
}

extern "C" __global__ __launch_bounds__(256, 1) void lstm_enc_kernel(
    const float* __restrict__ x,
    const float* __restrict__ Wih1, const float* __restrict__ Whh1,
    const float* __restrict__ bih1, const float* __restrict__ bhh1,
    const float* __restrict__ Wih2, const float* __restrict__ Whh2,
    const float* __restrict__ bih2, const float* __restrict__ bhh2,
    const float* __restrict__ Wfc,  const float* __restrict__ bfc,
    float* __restrict__ out)
{
    const int tid = threadIdx.x;
    const int l   = tid & 63;
    const int wv  = __builtin_amdgcn_readfirstlane(tid >> 6);   // 0..3
    const int be  = wv >> 1;                   // batch element in block
    const bool isL1 = ((wv & 1) == 0);         // waves 0,2 = L1; 1,3 = L2
    const int bg  = blockIdx.x * 2 + be;       // global batch index

    // h1 ring: 128 steps (2 chunks x 64), row t%128 = h1(t) as 64 fp16.
    __shared__ __align__(16) _Float16 ring[2][128][64];   // 32 KB
    __shared__ __align__(16) _Float16 h2r[2][2][32];      // h2 slots (t&1)

    const float kSs = -1.4426950408889634f;   // sigmoid pre-scale
    const float kSg = -2.8853900817779268f;   // tanh-form pre-scale

    if (isL1) {
        // ------------------- L1 wave: lane u = l owns unit u -------------------
        h8 wi[8], wf[8], wg[8], wo[8];
        const int ri = l, rf = 64 + l, rg = 128 + l, ro = 192 + l;
        #pragma unroll
        for (int j = 0; j < 8; ++j) {
            wi[j] = ldh8s(Whh1 + ri*64 + j*8, kSs);
            wf[j] = ldh8s(Whh1 + rf*64 + j*8, kSs);
            wg[j] = ldh8s(Whh1 + rg*64 + j*8, kSg);
            wo[j] = ldh8s(Whh1 + ro*64 + j*8, kSs);
        }
        const int wxi = pack16(Wih1[ri*2]*kSs, Wih1[ri*2+1]*kSs);
        const int wxf = pack16(Wih1[rf*2]*kSs, Wih1[rf*2+1]*kSs);
        const int wxg = pack16(Wih1[rg*2]*kSg, Wih1[rg*2+1]*kSg);
        const int wxo = pack16(Wih1[ro*2]*kSs, Wih1[ro*2+1]*kSs);
        const float bi_ = (bih1[ri] + bhh1[ri]) * kSs;
        const float bf_ = (bih1[rf] + bhh1[rf]) * kSs;
        const float bg_ = (bih1[rg] + bhh1[rg]) * kSg;
        const float bo_ = (bih1[ro] + bhh1[ro]) * kSs;

        // self-loaded x: lane s holds pack16(x(t=c*64+s)) for current chunk
        const float2* xb2 = (const float2*)(x + (size_t)bg * (TT * 2));
        const float2 v0 = xb2[l];
        int vxcur = pack16(v0.x, v0.y);            // chunk 0
        float2 vxn = xb2[64 + l];                  // chunk 1 in flight

        if (l < 32) ((int*)&ring[be][127][0])[l] = 0;   // h1(-1) = 0
        BARRIER();

        float cc = 0.f;
        _Float16* rw = &ring[be][0][0];
        const i4* rd = (const i4*)&ring[be][0][0];      // 8 i4 per row

// Per-j load->dot interleave: dot on H[0] starts as soon as its ds_read
// lands (counted lgkmcnt), instead of draining all 8 reads first.
// Summation order identical to R22 -> bit-identical results.
#define L1S(PR, CR, XV) { \
    const i4* Hp = rd + (PR)*8; \
    float ai = bi_, af = bf_, ag = bg_, ao = bo_; \
    _Pragma("unroll") for (int j = 0; j < 8; ++j) { \
        const i4 Hj = Hp[j]; \
        ai = dot8(wi[j], Hj, ai); af = dot8(wf[j], Hj, af); \
        ag = dot8(wg[j], Hj, ag); ao = dot8(wo[j], Hj, ao); } \
    const int xv_ = (XV); \
    ai = fdh(wxi, xv_, ai); af = fdh(wxf, xv_, af); \
    ag = fdh(wxg, xv_, ag); ao = fdh(wxo, xv_, ao); \
    const float gi = lgs(ai), gf = lgs(af), go = lgs(ao); \
    const float gg = fmaf(2.f, lgs(ag), -1.f); \
    cc = fmaf(gf, cc, gi * gg); \
    rw[(CR)*64 + l] = (_Float16)(go * tanh_(cc)); }

        #pragma unroll 1
        for (int c = 0; c <= NCH; ++c) {
            if (c < NCH) {
                const int base = (c & 1) * 64;
                const int p0 = (base ^ 64) + 63;   // last row of other chunk
                L1S(p0, base, __builtin_amdgcn_readlane(vxcur, 0))
                #pragma unroll 2
                for (int s = 1; s < 64; ++s) {
                    L1S(base + s - 1, base + s, __builtin_amdgcn_readlane(vxcur, s))
                }
                // rotate x buffers: pack chunk c+1, prefetch chunk c+2
                if (c + 1 < NCH) vxcur = pack16(vxn.x, vxn.y);
                if (c + 2 < NCH) vxn = xb2[(c + 2) * 64 + l];
            }
            BARRIER();
        }
#undef L1S
    } else {
        // --------- L2 wave: lane = (u = l&31, hf = l>>5); rows (i,f)|(g,o) ---------
        const int u = l & 31, hf = l >> 5;
        const float hff = (float)hf;
        const int rA = hf * 64 + u;        // i (hf=0) or g (hf=1)
        const int rB = hf * 64 + 32 + u;   // f (hf=0) or o (hf=1)
        const float kA = hf ? kSg : kSs;
        h8 wa[12], wb[12];
        #pragma unroll
        for (int j = 0; j < 8; ++j) {
            wa[j] = ldh8s(Wih2 + rA*64 + j*8, kA);
            wb[j] = ldh8s(Wih2 + rB*64 + j*8, kSs);
        }
        #pragma unroll
        for (int j = 0; j < 4; ++j) {
            wa[8+j] = ldh8s(Whh2 + rA*32 + j*8, kA);
            wb[8+j] = ldh8s(Whh2 + rB*32 + j*8, kSs);
        }
        const float ba_ = (bih2[rA] + bhh2[rA]) * kA;
        const float bb_ = (bih2[rB] + bhh2[rB]) * kSs;

        BARRIER();

        float c2 = 0.f;
        int hp2 = 0;                       // packed (h2[2p],h2[2p+1]) on even lanes; h2(-1)=0
        const i4* rdh = (const i4*)&ring[be][0][0];
        _Float16* q0 = &h2r[be][0][0];
        _Float16* q1 = &h2r[be][1][0];

// Dots+act on a RESIDENT H buffer (reads for the next row were issued
// earlier; counted lgkmcnt lets HB stay usable while newer reads fly).
#define L2SD(HB, QW) { \
    i4 G[4]; \
    _Pragma("unroll") for (int j = 0; j < 4; ++j) { \
        G[j].x = __builtin_amdgcn_readlane(hp2, j*8+0); \
        G[j].y = __builtin_amdgcn_readlane(hp2, j*8+2); \
        G[j].z = __builtin_amdgcn_readlane(hp2, j*8+4); \
        G[j].w = __builtin_amdgcn_readlane(hp2, j*8+6); } \
    float pa = ba_, pb = bb_; \
    _Pragma("unroll") for (int j = 0; j < 8; ++j) { \
        pa = dot8(wa[j], HB[j], pa); pb = dot8(wb[j], HB[j], pb); } \
    _Pragma("unroll") for (int j = 0; j < 4; ++j) { \
        pa = dot8(wa[8+j], G[j], pa); pb = dot8(wb[8+j], G[j], pb); } \
    const float sa = lgs(pa); \
    const float va = fmaf(hff, sa - 1.f, sa);   /* i or tanh-g */ \
    const float vb = lgs(pb);                   /* f or o      */ \
    const float oa = __shfl_xor(va, 32); \
    const float ob = __shfl_xor(vb, 32); \
    const float gi = hf ? oa : va, gf = hf ? ob : vb; \
    const float gg = hf ? va : oa, go = hf ? vb : ob; \
    c2 = fmaf(gf, c2, gi * gg); \
    const float h2n = go * tanh_(c2); \
    hp2 = pack16(h2n, qperm<0xB1>(h2n)); \
    if (!hf) (QW)[u] = (_Float16)h2n; }

        #pragma unroll 1
        for (int c = 0; c <= NCH; ++c) {
            if (c > 0) {
                const i4* rc = rdh + ((c - 1) & 1) * 64 * 8;   // chunk c-1 rows
                i4 Ha[8], Hb[8];
                #pragma unroll
                for (int j = 0; j < 8; ++j) Ha[j] = rc[j];     // row 0
                #pragma unroll 1
                for (int s = 0; s < 64; s += 2) {
                    const i4* rn1 = rc + (s + 1) * 8;          // issue row s+1
                    #pragma unroll
                    for (int j = 0; j < 8; ++j) Hb[j] = rn1[j];
                    L2SD(Ha, q0)                               // tau even -> slot 0
                    const i4* rn2 = rc + ((s + 2 < 64) ? (s + 2) : 0) * 8;
                    #pragma unroll
                    for (int j = 0; j < 8; ++j) Ha[j] = rn2[j];
                    L2SD(Hb, q1)                               // tau odd -> slot 1
                }
            }
            BARRIER();
        }
#undef L2SD

        // final h2(TT-1) in h2r[be][1] (4095 is odd -> slot 1)
        if (l < 16) {
            float sum = bfc[l];
            const float* wr = Wfc + l * 32;
            #pragma unroll
            for (int k = 0; k < 32; ++k) sum = fmaf(wr[k], (float)h2r[be][1][k], sum);
            out[bg * 16 + l] = sum;
        }
    }
}

extern "C" void kernel_launch(void* const* d_in, const int* in_sizes, int n_in,
                              void* d_out, int out_size, void* d_ws, size_t ws_size,
                              hipStream_t stream) {
    const float* x    = (const float*)d_in[0];
    const float* Wih1 = (const float*)d_in[1];
    const float* Whh1 = (const float*)d_in[2];
    const float* bih1 = (const float*)d_in[3];
    const float* bhh1 = (const float*)d_in[4];
    const float* Wih2 = (const float*)d_in[5];
    const float* Whh2 = (const float*)d_in[6];
    const float* bih2 = (const float*)d_in[7];
    const float* bhh2 = (const float*)d_in[8];
    const float* Wfc  = (const float*)d_in[9];
    const float* bfc  = (const float*)d_in[10];

    hipLaunchKernelGGL(lstm_enc_kernel, dim3(BB / 2), dim3(256), 0, stream,
        x, Wih1, Whh1, bih1, bhh1, Wih2, Whh2, bih2, bhh2, Wfc, bfc,
        (float*)d_out);
}

// Round 16
// 1482.170 us; speedup vs baseline: 1.9245x; 1.0514x over previous
//
#include <hip/hip_runtime.h>

// Encoder: 2-layer LSTM (H1=64, H2=32, IN=2), B=512, T=4096, + FC [32->16].
// R28 = R22 VERBATIM (session best, harness-verified 1483.7us) - final.
// Plateau ledger (dispatch cycles/step ~943 @ 2.4GHz): barrier-free chunked
// recurrence (R16 ++), L2 reg G-exchange (R21 +), x via readlane + L2
// streamed dbuf reads (R22 +). Probed and rejected: dot-chain split (R18 -),
// L1 reg-exchange (R20/R23 -), per-j load interleave (R27 -), wave
// stacking/destacking (R14/R19/R24 --), fused 1-wave both-layers (R17 --),
// permlane asm swap (R26 correctness fail). Remaining ~600cy/step is the
// serial core: DS write->broadcast-read turnaround (~150cy) + 128 fdot2
// issue (256cy) + transcendental tail (~80cy) + glue. Latency-bound, not a
// memory/compute roofline (HBM 0.07%, real VALU issue ~37%).
//  - L1 wave: lane u owns unit u, K=64 (32 dot8), h1 exchanged via LDS
//    ring (write fire-and-forget for L2; next-step broadcast reads);
//    x self-loaded, lane s holds step s's pack16 -> per-step v_readlane.
//  - L2 wave: lane=(u,hf), rows (i,f)|(g,o), K=96; h2 exchanged in
//    registers (qperm+pack16+readlane, bit-identical to LDS path);
//    last-chunk H rows streamed with Ha/Hb double-buffer; one
//    __shfl_xor(32) pair for the cross-half gate exchange.
//  - 128-step h1 ring decouples L1/L2 by one 64-step chunk; ONE lgkmcnt
//    barrier per chunk (65 total). Pre-scaled gates (i/f/o * -log2e,
//    g * -2log2e) feed rcp(1+exp2(p)) directly.
//  - 256 thr = {L1,L2} x 2 be, grid 256 (1 block/CU, 1 wave/SIMD).

#define TT 4096
#define BB 512
#define NCH 64   // chunks of 64 steps

typedef float    f4  __attribute__((ext_vector_type(4)));
typedef int      i4  __attribute__((ext_vector_type(4)));
typedef _Float16 h2v __attribute__((ext_vector_type(2)));
typedef _Float16 h8  __attribute__((ext_vector_type(8)));   // 4 VGPRs

__device__ __forceinline__ float fexp2(float x){ return __builtin_amdgcn_exp2f(x); }
__device__ __forceinline__ float frcp (float x){ return __builtin_amdgcn_rcpf(x); }
// logistic on a PRE-SCALED argument (scale folded into weights/bias).
__device__ __forceinline__ float lgs  (float p){ return frcp(1.0f + fexp2(p)); }
__device__ __forceinline__ float tanh_(float x){ return 1.0f - 2.0f * frcp(1.0f + fexp2(x * 2.8853900817779268f)); }

// Lightweight barrier: LDS-drain only; leaves global prefetch in flight.
#define BARRIER() asm volatile("s_waitcnt lgkmcnt(0)\n\ts_barrier" ::: "memory")

// DPP move. 0xB1=[1,0,3,2] within quads.
template<int CTRL>
__device__ __forceinline__ float qperm(float v){
  const int s = __builtin_bit_cast(int, v);
  return __builtin_bit_cast(float, __builtin_amdgcn_update_dpp(s, s, CTRL, 0xF, 0xF, true));
}
__device__ __forceinline__ h2v bch(int s){ return __builtin_bit_cast(h2v, s); }
__device__ __forceinline__ float dot8(h8 a, i4 bi, float c){
  const i4 ai = __builtin_bit_cast(i4, a);
  c = __builtin_amdgcn_fdot2(bch(ai.x), bch(bi.x), c, false);
  c = __builtin_amdgcn_fdot2(bch(ai.y), bch(bi.y), c, false);
  c = __builtin_amdgcn_fdot2(bch(ai.z), bch(bi.z), c, false);
  c = __builtin_amdgcn_fdot2(bch(ai.w), bch(bi.w), c, false);
  return c;
}
__device__ __forceinline__ float fdh(int a, int b, float c){
  return __builtin_amdgcn_fdot2(bch(a), bch(b), c, false);
}
__device__ __forceinline__ int pack16(float a, float b){
  h2v p; p.x = (_Float16)a; p.y = (_Float16)b;
  return __builtin_bit_cast(int, p);
}
__device__ __forceinline__ h8 ldh8s(const float* p, float s){
  const f4 a = ((const f4*)p)[0], b = ((const f4*)p)[1];
  h8 r;
  r[0]=(_Float16)(a.x*s); r[1]=(_Float16)(a.y*s); r[2]=(_Float16)(a.z*s); r[3]=(_Float16)(a.w*s);
  r[4]=(_Float16)(b.x*s); r[5]=(_Float16)(b.y*s); r[6]=(_Float16)(b.z*s); r[7]=(_Float16)(b.w*s);
  return r;
}

extern "C" __global__ __launch_bounds__(256, 1) void lstm_enc_kernel(
    const float* __restrict__ x,
    const float* __restrict__ Wih1, const float* __restrict__ Whh1,
    const float* __restrict__ bih1, const float* __restrict__ bhh1,
    const float* __restrict__ Wih2, const float* __restrict__ Whh2,
    const float* __restrict__ bih2, const float* __restrict__ bhh2,
    const float* __restrict__ Wfc,  const float* __restrict__ bfc,
    float* __restrict__ out)
{
    const int tid = threadIdx.x;
    const int l   = tid & 63;
    const int wv  = __builtin_amdgcn_readfirstlane(tid >> 6);   // 0..3
    const int be  = wv >> 1;                   // batch element in block
    const bool isL1 = ((wv & 1) == 0);         // waves 0,2 = L1; 1,3 = L2
    const int bg  = blockIdx.x * 2 + be;       // global batch index

    // h1 ring: 128 steps (2 chunks x 64), row t%128 = h1(t) as 64 fp16.
    __shared__ __align__(16) _Float16 ring[2][128][64];   // 32 KB
    __shared__ __align__(16) _Float16 h2r[2][2][32];      // h2 slots (t&1)

    const float kSs = -1.4426950408889634f;   // sigmoid pre-scale
    const float kSg = -2.8853900817779268f;   // tanh-form pre-scale

    if (isL1) {
        // ------------------- L1 wave: lane u = l owns unit u -------------------
        h8 wi[8], wf[8], wg[8], wo[8];
        const int ri = l, rf = 64 + l, rg = 128 + l, ro = 192 + l;
        #pragma unroll
        for (int j = 0; j < 8; ++j) {
            wi[j] = ldh8s(Whh1 + ri*64 + j*8, kSs);
            wf[j] = ldh8s(Whh1 + rf*64 + j*8, kSs);
            wg[j] = ldh8s(Whh1 + rg*64 + j*8, kSg);
            wo[j] = ldh8s(Whh1 + ro*64 + j*8, kSs);
        }
        const int wxi = pack16(Wih1[ri*2]*kSs, Wih1[ri*2+1]*kSs);
        const int wxf = pack16(Wih1[rf*2]*kSs, Wih1[rf*2+1]*kSs);
        const int wxg = pack16(Wih1[rg*2]*kSg, Wih1[rg*2+1]*kSg);
        const int wxo = pack16(Wih1[ro*2]*kSs, Wih1[ro*2+1]*kSs);
        const float bi_ = (bih1[ri] + bhh1[ri]) * kSs;
        const float bf_ = (bih1[rf] + bhh1[rf]) * kSs;
        const float bg_ = (bih1[rg] + bhh1[rg]) * kSg;
        const float bo_ = (bih1[ro] + bhh1[ro]) * kSs;

        // self-loaded x: lane s holds pack16(x(t=c*64+s)) for current chunk
        const float2* xb2 = (const float2*)(x + (size_t)bg * (TT * 2));
        const float2 v0 = xb2[l];
        int vxcur = pack16(v0.x, v0.y);            // chunk 0
        float2 vxn = xb2[64 + l];                  // chunk 1 in flight

        if (l < 32) ((int*)&ring[be][127][0])[l] = 0;   // h1(-1) = 0
        BARRIER();

        float cc = 0.f;
        _Float16* rw = &ring[be][0][0];
        const i4* rd = (const i4*)&ring[be][0][0];      // 8 i4 per row

#define L1S(PR, CR, XV) { \
    const i4* Hp = rd + (PR)*8; \
    i4 H[8]; \
    _Pragma("unroll") for (int j = 0; j < 8; ++j) H[j] = Hp[j]; \
    float ai = bi_, af = bf_, ag = bg_, ao = bo_; \
    _Pragma("unroll") for (int j = 0; j < 8; ++j) { \
        ai = dot8(wi[j], H[j], ai); af = dot8(wf[j], H[j], af); \
        ag = dot8(wg[j], H[j], ag); ao = dot8(wo[j], H[j], ao); } \
    const int xv_ = (XV); \
    ai = fdh(wxi, xv_, ai); af = fdh(wxf, xv_, af); \
    ag = fdh(wxg, xv_, ag); ao = fdh(wxo, xv_, ao); \
    const float gi = lgs(ai), gf = lgs(af), go = lgs(ao); \
    const float gg = fmaf(2.f, lgs(ag), -1.f); \
    cc = fmaf(gf, cc, gi * gg); \
    rw[(CR)*64 + l] = (_Float16)(go * tanh_(cc)); }

        #pragma unroll 1
        for (int c = 0; c <= NCH; ++c) {
            if (c < NCH) {
                const int base = (c & 1) * 64;
                const int p0 = (base ^ 64) + 63;   // last row of other chunk
                L1S(p0, base, __builtin_amdgcn_readlane(vxcur, 0))
                #pragma unroll 2
                for (int s = 1; s < 64; ++s) {
                    L1S(base + s - 1, base + s, __builtin_amdgcn_readlane(vxcur, s))
                }
                // rotate x buffers: pack chunk c+1, prefetch chunk c+2
                if (c + 1 < NCH) vxcur = pack16(vxn.x, vxn.y);
                if (c + 2 < NCH) vxn = xb2[(c + 2) * 64 + l];
            }
            BARRIER();
        }
#undef L1S
    } else {
        // --------- L2 wave: lane = (u = l&31, hf = l>>5); rows (i,f)|(g,o) ---------
        const int u = l & 31, hf = l >> 5;
        const float hff = (float)hf;
        const int rA = hf * 64 + u;        // i (hf=0) or g (hf=1)
        const int rB = hf * 64 + 32 + u;   // f (hf=0) or o (hf=1)
        const float kA = hf ? kSg : kSs;
        h8 wa[12], wb[12];
        #pragma unroll
        for (int j = 0; j < 8; ++j) {
            wa[j] = ldh8s(Wih2 + rA*64 + j*8, kA);
            wb[j] = ldh8s(Wih2 + rB*64 + j*8, kSs);
        }
        #pragma unroll
        for (int j = 0; j < 4; ++j) {
            wa[8+j] = ldh8s(Whh2 + rA*32 + j*8, kA);
            wb[8+j] = ldh8s(Whh2 + rB*32 + j*8, kSs);
        }
        const float ba_ = (bih2[rA] + bhh2[rA]) * kA;
        const float bb_ = (bih2[rB] + bhh2[rB]) * kSs;

        BARRIER();

        float c2 = 0.f;
        int hp2 = 0;                       // packed (h2[2p],h2[2p+1]) on even lanes; h2(-1)=0
        const i4* rdh = (const i4*)&ring[be][0][0];
        _Float16* q0 = &h2r[be][0][0];
        _Float16* q1 = &h2r[be][1][0];

// Dots+act on a RESIDENT H buffer (reads for the next row were issued
// earlier; counted lgkmcnt lets HB stay usable while newer reads fly).
#define L2SD(HB, QW) { \
    i4 G[4]; \
    _Pragma("unroll") for (int j = 0; j < 4; ++j) { \
        G[j].x = __builtin_amdgcn_readlane(hp2, j*8+0); \
        G[j].y = __builtin_amdgcn_readlane(hp2, j*8+2); \
        G[j].z = __builtin_amdgcn_readlane(hp2, j*8+4); \
        G[j].w = __builtin_amdgcn_readlane(hp2, j*8+6); } \
    float pa = ba_, pb = bb_; \
    _Pragma("unroll") for (int j = 0; j < 8; ++j) { \
        pa = dot8(wa[j], HB[j], pa); pb = dot8(wb[j], HB[j], pb); } \
    _Pragma("unroll") for (int j = 0; j < 4; ++j) { \
        pa = dot8(wa[8+j], G[j], pa); pb = dot8(wb[8+j], G[j], pb); } \
    const float sa = lgs(pa); \
    const float va = fmaf(hff, sa - 1.f, sa);   /* i or tanh-g */ \
    const float vb = lgs(pb);                   /* f or o      */ \
    const float oa = __shfl_xor(va, 32); \
    const float ob = __shfl_xor(vb, 32); \
    const float gi = hf ? oa : va, gf = hf ? ob : vb; \
    const float gg = hf ? va : oa, go = hf ? vb : ob; \
    c2 = fmaf(gf, c2, gi * gg); \
    const float h2n = go * tanh_(c2); \
    hp2 = pack16(h2n, qperm<0xB1>(h2n)); \
    if (!hf) (QW)[u] = (_Float16)h2n; }

        #pragma unroll 1
        for (int c = 0; c <= NCH; ++c) {
            if (c > 0) {
                const i4* rc = rdh + ((c - 1) & 1) * 64 * 8;   // chunk c-1 rows
                i4 Ha[8], Hb[8];
                #pragma unroll
                for (int j = 0; j < 8; ++j) Ha[j] = rc[j];     // row 0
                #pragma unroll 1
                for (int s = 0; s < 64; s += 2) {
                    const i4* rn1 = rc + (s + 1) * 8;          // issue row s+1
                    #pragma unroll
                    for (int j = 0; j < 8; ++j) Hb[j] = rn1[j];
                    L2SD(Ha, q0)                               // tau even -> slot 0
                    const i4* rn2 = rc + ((s + 2 < 64) ? (s + 2) : 0) * 8;
                    #pragma unroll
                    for (int j = 0; j < 8; ++j) Ha[j] = rn2[j];
                    L2SD(Hb, q1)                               // tau odd -> slot 1
                }
            }
            BARRIER();
        }
#undef L2SD

        // final h2(TT-1) in h2r[be][1] (4095 is odd -> slot 1)
        if (l < 16) {
            float sum = bfc[l];
            const float* wr = Wfc + l * 32;
            #pragma unroll
            for (int k = 0; k < 32; ++k) sum = fmaf(wr[k], (float)h2r[be][1][k], sum);
            out[bg * 16 + l] = sum;
        }
    }
}

extern "C" void kernel_launch(void* const* d_in, const int* in_sizes, int n_in,
                              void* d_out, int out_size, void* d_ws, size_t ws_size,
                              hipStream_t stream) {
    const float* x    = (const float*)d_in[0];
    const float* Wih1 = (const float*)d_in[1];
    const float* Whh1 = (const float*)d_in[2];
    const float* bih1 = (const float*)d_in[3];
    const float* bhh1 = (const float*)d_in[4];
    const float* Wih2 = (const float*)d_in[5];
    const float* Whh2 = (const float*)d_in[6];
    const float* bih2 = (const float*)d_in[7];
    const float* bhh2 = (const float*)d_in[8];
    const float* Wfc  = (const float*)d_in[9];
    const float* bfc  = (const float*)d_in[10];

    hipLaunchKernelGGL(lstm_enc_kernel, dim3(BB / 2), dim3(256), 0, stream,
        x, Wih1, Whh1, bih1, bhh1, Wih2, Whh2, bih2, bhh2, Wfc, bfc,
        (float*)d_out);
}